// Round 1
// 1034.695 us; speedup vs baseline: 1.0340x; 1.0340x over previous
//
#include <hip/hip_runtime.h>
#include <cstdint>

// EarthAttention3D on gfx950 — f16 MFMA path.
// Stages: cvt x->f16 | transpose w's | QKV GEMM (mfma 16x16x32_f16, global_load_lds)
//         | fused attention per (w,h) with bias-in-registers, batch loop
//         | proj GEMM.
// This rev: GEMMs get (a) XCD-chunked column-fast block swizzle (A-panel L2 reuse),
//           (b) double-buffered LDS 2-phase pipeline (prefetch next K-tile during MFMA).

typedef _Float16 f16;
typedef _Float16 f16x8 __attribute__((ext_vector_type(8)));
typedef _Float16 f16x4v __attribute__((ext_vector_type(4)));
typedef float f32x4 __attribute__((ext_vector_type(4)));

#define NW_ 64
#define HEADS_ 12
#define DIM_ 384
#define BATCH_ 15
#define NTOK_ 144
#define HD_ 32
#define MTOK_ (BATCH_*NW_*NTOK_)   // 138240
#define NWH_ (BATCH_*NW_*HEADS_)   // 11520

__device__ __forceinline__ void load16_lds(const void* g, void* l) {
    __builtin_amdgcn_global_load_lds(
        (const __attribute__((address_space(1))) uint32_t*)g,
        (__attribute__((address_space(3))) uint32_t*)l,
        16, 0, 0);
}

__device__ __forceinline__ f32x4 fzero4() {
    f32x4 z; z[0]=0.f; z[1]=0.f; z[2]=0.f; z[3]=0.f; return z;
}

// ---------------- pre-pass: fp32 -> f16 ----------------
__global__ void cvt_f32_to_f16(const float* __restrict__ src, f16* __restrict__ dst, int n4) {
    int i = blockIdx.x * blockDim.x + threadIdx.x;
    int stride = gridDim.x * blockDim.x;
    for (; i < n4; i += stride) {
        float4 v = ((const float4*)src)[i];
        f16x4v o;
        o[0] = (f16)v.x; o[1] = (f16)v.y; o[2] = (f16)v.z; o[3] = (f16)v.w;
        *(f16x4v*)(dst + 4*(size_t)i) = o;
    }
}

// src [K][N] fp32 -> dst [N][K] f16  (coalesced writes)
__global__ void transpose_cvt(const float* __restrict__ src, f16* __restrict__ dst, int K, int N) {
    int i = blockIdx.x * blockDim.x + threadIdx.x;
    if (i >= K*N) return;
    int n = i / K;
    int k = i - n*K;
    dst[i] = (f16)src[k*N + n];
}

// ---------------- QKV GEMM ----------------
// A: x_f16 [MTOK][384]; Bt: wt_qkv [1152][384] (= w_qkv^T).
// C[row][col] scattered: q[head][n][d], k[head][n][d], v[head][d][n]  (f16)
// Grid: 9720 linear blocks; XCD-chunked bijective swizzle (9720 = 8*1215),
// column index fastest within an XCD chunk so A row-panels are L2-reused 9x.
__global__ __launch_bounds__(256) void qkv_gemm(
    const f16* __restrict__ A, const f16* __restrict__ Bt,
    const float* __restrict__ bias,
    f16* __restrict__ qws, f16* __restrict__ kws, f16* __restrict__ vws)
{
    constexpr int BK = 32;
    constexpr int NT = DIM_/BK;  // 12 K-steps
    __shared__ __align__(16) f16 Asm[2][128*BK];
    __shared__ __align__(16) f16 Bsm[2][128*BK];
    const int tid  = threadIdx.x;
    const int lane = tid & 63;
    const int wave = tid >> 6;
    const int l15  = lane & 15;
    const int quad = lane >> 4;
    const int wr = wave >> 1, wc = wave & 1;

    unsigned lin = blockIdx.x;
    lin = (lin & 7u) * 1215u + (lin >> 3);   // XCD-chunked, bijective (9720 % 8 == 0)
    const int row0 = (int)(lin / 9u) * 128;
    const int col0 = (int)(lin % 9u) * 128;

    f32x4 acc[4][4];
    #pragma unroll
    for (int i = 0; i < 4; ++i)
        #pragma unroll
        for (int j = 0; j < 4; ++j) acc[i][j] = fzero4();

    auto stage = [&](int kt, int b) {
        const int k0 = kt * BK;
        #pragma unroll
        for (int cc = 0; cc < 2; ++cc) {
            int chunk  = wave*2 + cc;          // 0..7
            int flat16 = chunk*64 + lane;      // 16B units; r = /4, c16 = %4
            int r   = flat16 >> 2;
            int c16 = flat16 & 3;
            load16_lds(&A [(size_t)(row0 + r)*DIM_ + k0 + c16*8], (char*)(&Asm[b][0]) + chunk*1024);
            load16_lds(&Bt[(size_t)(col0 + r)*DIM_ + k0 + c16*8], (char*)(&Bsm[b][0]) + chunk*1024);
        }
    };
    auto compute = [&](int b) {
        f16x8 af[4], bf[4];
        #pragma unroll
        for (int i = 0; i < 4; ++i)
            af[i] = *(const f16x8*)&Asm[b][(wr*64 + i*16 + l15)*BK + quad*8];
        #pragma unroll
        for (int j = 0; j < 4; ++j)
            bf[j] = *(const f16x8*)&Bsm[b][(wc*64 + j*16 + l15)*BK + quad*8];
        #pragma unroll
        for (int i = 0; i < 4; ++i)
            #pragma unroll
            for (int j = 0; j < 4; ++j)
                acc[i][j] = __builtin_amdgcn_mfma_f32_16x16x32_f16(af[i], bf[j], acc[i][j], 0, 0, 0);
    };

    // 2-phase double-buffered pipeline: prefetch tile kt+1 while computing kt.
    stage(0, 0);
    asm volatile("s_waitcnt vmcnt(0)" ::: "memory");
    __builtin_amdgcn_s_barrier();
    __builtin_amdgcn_sched_barrier(0);
    int cur = 0;
    for (int kt = 0; kt < NT-1; ++kt) {
        stage(kt+1, cur^1);
        compute(cur);
        asm volatile("s_waitcnt vmcnt(0) lgkmcnt(0)" ::: "memory");
        __builtin_amdgcn_s_barrier();
        __builtin_amdgcn_sched_barrier(0);
        cur ^= 1;
    }
    compute(cur);

    // epilogue: col -> (which, h, d); row -> (bw, n)
    const int which = col0 / DIM_;     // block fully inside q, k, or v
    #pragma unroll
    for (int j = 0; j < 4; ++j) {
        int col = col0 + wc*64 + j*16 + l15;
        float bq = bias[col];
        int rem = col - which*DIM_;
        int h = rem >> 5, d = rem & 31;
        #pragma unroll
        for (int i = 0; i < 4; ++i) {
            int rowb = row0 + wr*64 + i*16 + quad*4;
            #pragma unroll
            for (int r = 0; r < 4; ++r) {
                int row = rowb + r;
                int bw  = row / NTOK_;
                int n   = row - bw*NTOK_;
                int head = bw*HEADS_ + h;
                f16 hv = (f16)(acc[i][j][r] + bq);
                if (which == 0)      qws[(size_t)head*NTOK_*HD_ + n*HD_ + d] = hv;
                else if (which == 1) kws[(size_t)head*NTOK_*HD_ + n*HD_ + d] = hv;
                else                 vws[(size_t)head*HD_*NTOK_ + d*NTOK_ + n] = hv;
            }
        }
    }
}

// ---------------- fused attention ----------------
// grid = 768 blocks (w,h); 576 threads = 9 waves (one 16-row Q tile each);
// loops b=0..14 reusing bias gathered into registers.
__global__ __launch_bounds__(576) void attention(
    const f16* __restrict__ qws, const f16* __restrict__ kws, const f16* __restrict__ vws,
    const float* __restrict__ bias_table, const int* __restrict__ pos_idx,
    const float* __restrict__ mask, f16* __restrict__ ows)
{
    constexpr int KPAD = 40;   // Ksm row stride (f16)
    constexpr int VPAD = 168;  // Vt / P row stride (f16), 160 used
    // [Vt 10752B][ K 11520B overlaid by P strips 48384B ] = 59136 B
    __shared__ __align__(16) char smem[10752 + 48384];
    f16* Vt  = (f16*)smem;            // [32][168]
    f16* Ksm = (f16*)(smem + 10752);  // [144][40]
    f16* Pst = (f16*)(smem + 10752);  // [9][16][168]

    const int tid  = threadIdx.x;
    const int lane = tid & 63;
    const int wv   = tid >> 6;    // 0..8: Q row tile
    const int l15  = lane & 15;
    const int quad = lane >> 4;

    const int wh = blockIdx.x;
    const int w  = wh / HEADS_;
    const int h  = wh - w*HEADS_;

    // bias gather (once per block): n = wv*16+quad*4+r, m = j*16+l15
    float brg[9][4];
    #pragma unroll
    for (int j = 0; j < 9; ++j) {
        int m = j*16 + l15;
        #pragma unroll
        for (int r = 0; r < 4; ++r) {
            int n = wv*16 + quad*4 + r;
            int idx = pos_idx[n*NTOK_ + m];
            brg[j][r] = bias_table[(size_t)idx*(NW_*HEADS_) + w*HEADS_ + h];
        }
    }

    // zero Vt pad cols [144,160) once
    if (tid < 64) {
        int d = tid >> 1, m0 = 144 + (tid & 1)*8;
        uint4 z = {0u,0u,0u,0u};
        *(uint4*)&Vt[d*VPAD + m0] = z;
    }

    const float scale = 0.17677669529663687f;  // 32^-0.5

    for (int b = 0; b < BATCH_; ++b) {
        const int bwh = (b*NW_ + w)*HEADS_ + h;
        const f16* qh = qws + (size_t)bwh*NTOK_*HD_;
        const f16* kh = kws + (size_t)bwh*NTOK_*HD_;
        const f16* vh = vws + (size_t)bwh*HD_*NTOK_;

        __syncthreads();  // prior iter's LDS consumers done
        {   // stage K [144][32]->Ksm[144][40] and V^T [32][144]->Vt[32][168]
            int flat = tid*8;
            int n = flat >> 5, d = flat & 31;
            *(uint4*)&Ksm[n*KPAD + d] = *(const uint4*)&kh[flat];
            int dv = flat / NTOK_;
            int mv = flat - dv*NTOK_;
            *(uint4*)&Vt[dv*VPAD + mv] = *(const uint4*)&vh[flat];
        }
        // Q A-frag: row = l15, k = quad*8..+8
        int nq = wv*16 + l15;
        f16x8 qf = *(const f16x8*)&qh[nq*HD_ + quad*8];
        __syncthreads();  // staging visible

        // S = Q K^T : 9 col tiles, one K=32 step each
        f32x4 sfr[9];
        #pragma unroll
        for (int j = 0; j < 9; ++j) {
            f16x8 kf = *(const f16x8*)&Ksm[(j*16 + l15)*KPAD + quad*8];
            sfr[j] = __builtin_amdgcn_mfma_f32_16x16x32_f16(qf, kf, fzero4(), 0, 0, 0);
        }
        __syncthreads();  // all K reads done; P strips may overwrite K region

        // softmax over 144 cols (rows live in 16-lane groups)
        float p[9][4], rmax[4], rsum[4];
        #pragma unroll
        for (int r = 0; r < 4; ++r) rmax[r] = -1e30f;
        const float* mrow = mask + (size_t)b*NTOK_*NTOK_;
        #pragma unroll
        for (int j = 0; j < 9; ++j) {
            int m = j*16 + l15;
            #pragma unroll
            for (int r = 0; r < 4; ++r) {
                int n = wv*16 + quad*4 + r;
                float s = sfr[j][r]*scale + brg[j][r] + mrow[n*NTOK_ + m];
                p[j][r] = s;
                rmax[r] = fmaxf(rmax[r], s);
            }
        }
        #pragma unroll
        for (int r = 0; r < 4; ++r) {
            float v = rmax[r];
            #pragma unroll
            for (int off = 1; off < 16; off <<= 1)
                v = fmaxf(v, __shfl_xor(v, off, 64));
            rmax[r] = v;
        }
        #pragma unroll
        for (int r = 0; r < 4; ++r) rsum[r] = 0.f;
        #pragma unroll
        for (int j = 0; j < 9; ++j)
            #pragma unroll
            for (int r = 0; r < 4; ++r) {
                float e = __expf(p[j][r] - rmax[r]);
                p[j][r] = e;
                rsum[r] += e;
            }
        #pragma unroll
        for (int r = 0; r < 4; ++r) {
            float v = rsum[r];
            #pragma unroll
            for (int off = 1; off < 16; off <<= 1)
                v += __shfl_xor(v, off, 64);
            rsum[r] = 1.0f / v;
        }

        // write normalized P (C-layout) into own LDS strip; zero pad cols
        f16* Pw = Pst + wv*16*VPAD;
        #pragma unroll
        for (int j = 0; j < 9; ++j) {
            int m = j*16 + l15;
            #pragma unroll
            for (int r = 0; r < 4; ++r)
                Pw[(quad*4 + r)*VPAD + m] = (f16)(p[j][r]*rsum[r]);
        }
        if (lane < 32) {
            int row = lane >> 1, m0 = 144 + (lane & 1)*8;
            uint4 z = {0u,0u,0u,0u};
            *(uint4*)&Pw[row*VPAD + m0] = z;
        }

        // O = P V : 5 K=32 steps (wave-local LDS round trip; no barrier needed)
        f32x4 o0 = fzero4(), o1 = fzero4();
        #pragma unroll
        for (int s = 0; s < 5; ++s) {
            f16x8 pa = *(const f16x8*)&Pw[l15*VPAD + s*32 + quad*8];
            f16x8 v0 = *(const f16x8*)&Vt[l15*VPAD + s*32 + quad*8];
            f16x8 v1 = *(const f16x8*)&Vt[(16 + l15)*VPAD + s*32 + quad*8];
            o0 = __builtin_amdgcn_mfma_f32_16x16x32_f16(pa, v0, o0, 0, 0, 0);
            o1 = __builtin_amdgcn_mfma_f32_16x16x32_f16(pa, v1, o1, 0, 0, 0);
        }

        // epilogue: O[n][d] -> ows[bw][n][h*32+d]  (f16)
        const int bw = b*NW_ + w;
        #pragma unroll
        for (int r = 0; r < 4; ++r) {
            int n = wv*16 + quad*4 + r;
            size_t base = ((size_t)bw*NTOK_ + n)*DIM_ + h*HD_;
            ows[base + l15]      = (f16)o0[r];
            ows[base + 16 + l15] = (f16)o1[r];
        }
    }
}

// ---------------- proj GEMM ----------------
// A: o_f16 [MTOK][384]; Bt: wt_proj [384][384]; out fp32 [MTOK][384]
// Grid: 3240 linear blocks; XCD-chunked swizzle (3240 = 8*405), column fastest.
__global__ __launch_bounds__(256) void proj_gemm(
    const f16* __restrict__ A, const f16* __restrict__ Bt,
    const float* __restrict__ bias, float* __restrict__ out)
{
    constexpr int BK = 32;
    constexpr int NT = DIM_/BK;
    __shared__ __align__(16) f16 Asm[2][128*BK];
    __shared__ __align__(16) f16 Bsm[2][128*BK];
    const int tid  = threadIdx.x;
    const int lane = tid & 63;
    const int wave = tid >> 6;
    const int l15  = lane & 15;
    const int quad = lane >> 4;
    const int wr = wave >> 1, wc = wave & 1;

    unsigned lin = blockIdx.x;
    lin = (lin & 7u) * 405u + (lin >> 3);    // XCD-chunked, bijective (3240 % 8 == 0)
    const int row0 = (int)(lin / 3u) * 128;
    const int col0 = (int)(lin % 3u) * 128;

    f32x4 acc[4][4];
    #pragma unroll
    for (int i = 0; i < 4; ++i)
        #pragma unroll
        for (int j = 0; j < 4; ++j) acc[i][j] = fzero4();

    auto stage = [&](int kt, int b) {
        const int k0 = kt * BK;
        #pragma unroll
        for (int cc = 0; cc < 2; ++cc) {
            int chunk  = wave*2 + cc;
            int flat16 = chunk*64 + lane;
            int r   = flat16 >> 2;
            int c16 = flat16 & 3;
            load16_lds(&A [(size_t)(row0 + r)*DIM_ + k0 + c16*8], (char*)(&Asm[b][0]) + chunk*1024);
            load16_lds(&Bt[(size_t)(col0 + r)*DIM_ + k0 + c16*8], (char*)(&Bsm[b][0]) + chunk*1024);
        }
    };
    auto compute = [&](int b) {
        f16x8 af[4], bf[4];
        #pragma unroll
        for (int i = 0; i < 4; ++i)
            af[i] = *(const f16x8*)&Asm[b][(wr*64 + i*16 + l15)*BK + quad*8];
        #pragma unroll
        for (int j = 0; j < 4; ++j)
            bf[j] = *(const f16x8*)&Bsm[b][(wc*64 + j*16 + l15)*BK + quad*8];
        #pragma unroll
        for (int i = 0; i < 4; ++i)
            #pragma unroll
            for (int j = 0; j < 4; ++j)
                acc[i][j] = __builtin_amdgcn_mfma_f32_16x16x32_f16(af[i], bf[j], acc[i][j], 0, 0, 0);
    };

    stage(0, 0);
    asm volatile("s_waitcnt vmcnt(0)" ::: "memory");
    __builtin_amdgcn_s_barrier();
    __builtin_amdgcn_sched_barrier(0);
    int cur = 0;
    for (int kt = 0; kt < NT-1; ++kt) {
        stage(kt+1, cur^1);
        compute(cur);
        asm volatile("s_waitcnt vmcnt(0) lgkmcnt(0)" ::: "memory");
        __builtin_amdgcn_s_barrier();
        __builtin_amdgcn_sched_barrier(0);
        cur ^= 1;
    }
    compute(cur);

    #pragma unroll
    for (int j = 0; j < 4; ++j) {
        int col = col0 + wc*64 + j*16 + l15;
        float bp = bias[col];
        #pragma unroll
        for (int i = 0; i < 4; ++i) {
            int rowb = row0 + wr*64 + i*16 + quad*4;
            #pragma unroll
            for (int r = 0; r < 4; ++r)
                out[(size_t)(rowb + r)*DIM_ + col] = acc[i][j][r] + bp;
        }
    }
}

// ---------------- launcher ----------------
extern "C" void kernel_launch(void* const* d_in, const int* in_sizes, int n_in,
                              void* d_out, int out_size, void* d_ws, size_t ws_size,
                              hipStream_t stream)
{
    const float* x      = (const float*)d_in[0];
    const float* mask   = (const float*)d_in[1];
    const float* w_qkv  = (const float*)d_in[2];
    const float* b_qkv  = (const float*)d_in[3];
    const float* w_proj = (const float*)d_in[4];
    const float* b_proj = (const float*)d_in[5];
    const float* btab   = (const float*)d_in[6];
    const int*   pidx   = (const int*)d_in[7];
    float* out = (float*)d_out;

    constexpr size_t X16_B = (size_t)MTOK_*DIM_*2;        // 106,168,320
    constexpr size_t WTQ_B = (size_t)1152*384*2;          // 884,736
    constexpr size_t WTP_B = (size_t)384*384*2;           // 294,912
    constexpr size_t HEAD_B = (size_t)NWH_*NTOK_*HD_*2;   // 106,168,320

    char* ws = (char*)d_ws;
    f16* x16 = (f16*)ws;
    f16* wtq = (f16*)(ws + X16_B);
    f16* wtp = (f16*)(ws + X16_B + WTQ_B);
    f16* qws = (f16*)(ws + X16_B + WTQ_B + WTP_B);
    f16* kws = (f16*)((char*)qws + HEAD_B);
    f16* vws = (f16*)((char*)kws + HEAD_B);
    f16* ows = x16;  // x_f16 is dead after qkv_gemm; reuse for attention output

    cvt_f32_to_f16<<<8192, 256, 0, stream>>>(x, x16, MTOK_*DIM_/4);
    transpose_cvt<<<(384*1152 + 255)/256, 256, 0, stream>>>(w_qkv, wtq, 384, 1152);
    transpose_cvt<<<(384*384  + 255)/256, 256, 0, stream>>>(w_proj, wtp, 384, 384);
    qkv_gemm<<<9720, 256, 0, stream>>>(x16, wtq, b_qkv, qws, kws, vws);
    attention<<<NW_*HEADS_, 576, 0, stream>>>(qws, kws, vws, btab, pidx, mask, ows);
    proj_gemm<<<3240, 256, 0, stream>>>(ows, wtp, b_proj, out);
}